// Round 1
// 251.206 us; speedup vs baseline: 1.0111x; 1.0111x over previous
//
#include <hip/hip_runtime.h>
#include <cstdint>
#include <cstddef>

// ---------------------------------------------------------------------------
// Attention_84155589198714: qkv = ctx @ W + b; causal softmax(q k^T / sqrt(N)); @ v
// B=4, N=2048, D=1024. All GEMMs in bf16 MFMA (16x16x32), fp32 accumulate.
//
// R2: XOR bank swizzle (conflicts -> 0); gld16 mainloop = 700 TF at 6 blk/CU.
// R8: 128x64 scores/pv tiles (occupancy) -> 241-254 us total.
// R9: fused QKV projection as ONE 256x256-tile, 8-wave, 4-phase/K-tile kernel
//   with counted vmcnt (T3+T4) + setprio (T5).  Old k_gemm_qk was 641 TF at
//   MfmaUtil 26% -- the 2-barrier m97 structure's stall.  Schedule derivation:
//   per K-tile 4 half-tile slots staged in consumption order (A-lo, B-lo,
//   B-hi, A-hi), phase p of tile t issues slot p of tile t+1 into buf^1.
//   Steady state vmcnt(6) at phases 0,1,2 (3 half-tiles in flight), none at
//   phase 3; drain tile uses 4/2/0 (matches guide's epilogue -- schedule
//   cross-validated).  Every counted wait precedes a barrier -> cross-wave
//   staging visibility.  LDS 128 KiB, 1 blk/CU, 2 waves/SIMD.
// ---------------------------------------------------------------------------

typedef __attribute__((ext_vector_type(8))) __bf16 bf16x8;
typedef __attribute__((ext_vector_type(4))) float f32x4;

__device__ inline unsigned short f2bf(float f) {
  unsigned u = __float_as_uint(f);
  u = (u + 0x7FFFu + ((u >> 16) & 1u)) >> 16;  // RNE
  return (unsigned short)u;
}

__device__ inline void gld16(const void* g, void* l) {
  __builtin_amdgcn_global_load_lds(
      (const __attribute__((address_space(1))) unsigned int*)g,
      (__attribute__((address_space(3))) unsigned int*)l, 16, 0, 0);
}

// ===================== 256x256 fused-QKV tile machinery ====================
// LDS per K-tile buffer: 256 rows x 64 cols bf16, row r at r*64, 8-elem chunk
// c of row r at slot c^(r&7) (XOR bank swizzle, proven 0-conflict).
// 8 waves as 2(M) x 4(N); wave tile 128x64; acc[8][4] f32x4.
// Half-tile slots (128 rows each, 2 gld16/wave):
//   A-lo: rows with ((r>>6)&1)==0   A-hi: ==1   (aligned to wave mi-halves)
//   B-lo: rows with ((r>>5)&1)==0   B-hi: ==1   (aligned to wave nj-halves)

__device__ inline void stage_Ahalf(const unsigned short* Agb, int k0,
                                   unsigned short* Abuf, int half,
                                   int wave, int lrow, int lcol) {
#pragma unroll
  for (int i = 0; i < 2; i++) {
    const int c = wave * 2 + i;
    const int rg = ((c >> 3) << 7) + ((c & 7) << 3) + (half << 6);
    gld16(Agb + (size_t)(rg + lrow) * 1024 + k0 + lcol, Abuf + rg * 64);
  }
}

__device__ inline void stage_Bhalf(const unsigned short* Bgb, int k0,
                                   unsigned short* Bbuf, int half,
                                   int wave, int lrow, int lcol) {
#pragma unroll
  for (int i = 0; i < 2; i++) {
    const int c = wave * 2 + i;
    const int rg = ((c >> 2) << 6) + ((c & 3) << 3) + (half << 5);
    gld16(Bgb + (size_t)(rg + lrow) * 1024 + k0 + lcol, Bbuf + rg * 64);
  }
}

__device__ inline void read_Ahalf(const unsigned short* buf, int wm, int half,
                                  int lane, bf16x8 (&a)[4][2]) {
#pragma unroll
  for (int ks = 0; ks < 2; ks++) {
    const int csw = ((((ks << 2) + (lane >> 4)) ^ (lane & 7)) << 3);
#pragma unroll
    for (int mi = 0; mi < 4; mi++) {
      const int R = wm * 128 + half * 64 + mi * 16 + (lane & 15);
      a[mi][ks] = *(const bf16x8*)&buf[R * 64 + csw];
    }
  }
}

__device__ inline void read_Bhalf(const unsigned short* buf, int wn, int half,
                                  int lane, bf16x8 (&b)[2][2]) {
#pragma unroll
  for (int ks = 0; ks < 2; ks++) {
    const int csw = ((((ks << 2) + (lane >> 4)) ^ (lane & 7)) << 3);
#pragma unroll
    for (int nj = 0; nj < 2; nj++) {
      const int R = wn * 64 + half * 32 + nj * 16 + (lane & 15);
      b[nj][ks] = *(const bf16x8*)&buf[R * 64 + csw];
    }
  }
}

// 16 MFMA: one C-quadrant x K=64. ks outer -> 8 independent then 8 dep@8.
__device__ inline void mma_quad(const bf16x8 (&a)[4][2], const bf16x8 (&b)[2][2],
                                f32x4 (&acc)[8][4], const int ah, const int bh) {
#pragma unroll
  for (int ks = 0; ks < 2; ks++)
#pragma unroll
    for (int mi = 0; mi < 4; mi++)
#pragma unroll
      for (int nj = 0; nj < 2; nj++)
        acc[ah * 4 + mi][bh * 2 + nj] = __builtin_amdgcn_mfma_f32_16x16x32_bf16(
            b[nj][ks], a[mi][ks], acc[ah * 4 + mi][bh * 2 + nj], 0, 0, 0);
}

#define QKV_FENCE()                         \
  __builtin_amdgcn_s_barrier();             \
  asm volatile("" ::: "memory");            \
  __builtin_amdgcn_sched_barrier(0)

template <bool STAGE, int V0, int V1, int V2>
__device__ inline void qkv_tile(const unsigned short* Agb, const unsigned short* Bgb,
                                int k0n, const unsigned short* Ar, const unsigned short* Br,
                                unsigned short* Aw, unsigned short* Bw,
                                int wave, int lane, int wm, int wn,
                                f32x4 (&acc)[8][4]) {
  const int lrow = lane >> 3;
  const int lcol = ((lane & 7) ^ lrow) * 8;
  bf16x8 aLo[4][2], aHi[4][2], bLo[2][2], bHi[2][2];
  // ---- phase 0: Q(A-lo,B-lo); stage slot0 = A-lo(next)
  if (STAGE) stage_Ahalf(Agb, k0n, Aw, 0, wave, lrow, lcol);
  asm volatile("s_waitcnt vmcnt(%0)" ::"i"(V0) : "memory");
  QKV_FENCE();
  read_Ahalf(Ar, wm, 0, lane, aLo);
  read_Bhalf(Br, wn, 0, lane, bLo);
  __builtin_amdgcn_s_setprio(1);
  mma_quad(aLo, bLo, acc, 0, 0);
  __builtin_amdgcn_s_setprio(0);
  __builtin_amdgcn_sched_barrier(0);
  __builtin_amdgcn_s_barrier();
  // ---- phase 1: Q(A-lo,B-hi); stage slot1 = B-lo(next)
  if (STAGE) stage_Bhalf(Bgb, k0n, Bw, 0, wave, lrow, lcol);
  asm volatile("s_waitcnt vmcnt(%0)" ::"i"(V1) : "memory");
  QKV_FENCE();
  read_Bhalf(Br, wn, 1, lane, bHi);
  __builtin_amdgcn_s_setprio(1);
  mma_quad(aLo, bHi, acc, 0, 1);
  __builtin_amdgcn_s_setprio(0);
  __builtin_amdgcn_sched_barrier(0);
  __builtin_amdgcn_s_barrier();
  // ---- phase 2: Q(A-hi,B-hi); stage slot2 = B-hi(next)
  if (STAGE) stage_Bhalf(Bgb, k0n, Bw, 1, wave, lrow, lcol);
  asm volatile("s_waitcnt vmcnt(%0)" ::"i"(V2) : "memory");
  QKV_FENCE();
  read_Ahalf(Ar, wm, 1, lane, aHi);
  __builtin_amdgcn_s_setprio(1);
  mma_quad(aHi, bHi, acc, 1, 1);
  __builtin_amdgcn_s_setprio(0);
  __builtin_amdgcn_sched_barrier(0);
  __builtin_amdgcn_s_barrier();
  // ---- phase 3: Q(A-hi,B-lo); stage slot3 = A-hi(next); no new LDS reads
  if (STAGE) stage_Ahalf(Agb, k0n, Aw, 1, wave, lrow, lcol);
  __builtin_amdgcn_s_setprio(1);
  mma_quad(aHi, bLo, acc, 1, 0);
  __builtin_amdgcn_s_setprio(0);
  __builtin_amdgcn_sched_barrier(0);
  __builtin_amdgcn_s_barrier();
}

// qkv fused: A=ctx bf16 [8192][1024], Wt [3072][1024]. n-blocks 0-7 -> qk
// [8192][2048] bf16; n-blocks 8-11 -> vT [4][1024][2048] bf16 (transposed).
__global__ __launch_bounds__(512, 2) void k_gemm_qkv(
    const unsigned short* __restrict__ A, const unsigned short* __restrict__ Wt,
    const float* __restrict__ bias, unsigned short* __restrict__ qk,
    unsigned short* __restrict__ vT) {
  __shared__ unsigned short sA[2 * 16384];
  __shared__ unsigned short sB[2 * 16384];
  // XCD-aware swizzle: 384 blocks, 384 % 8 == 0 -> bijective simple form.
  const int bid = blockIdx.y * 12 + blockIdx.x;
  const int swz = (bid & 7) * 48 + (bid >> 3);
  const int nb = swz % 12, mb = swz / 12;
  const int tN0 = nb * 256, tM0 = mb * 256;
  const unsigned short* Agb = A + (size_t)tM0 * 1024;
  const unsigned short* Bgb = Wt + (size_t)tN0 * 1024;
  const int lane = threadIdx.x & 63, wave = threadIdx.x >> 6;
  const int wm = wave >> 2, wn = wave & 3;
  const int lrow = lane >> 3, lcol = ((lane & 7) ^ lrow) * 8;

  f32x4 acc[8][4];
#pragma unroll
  for (int mi = 0; mi < 8; mi++)
#pragma unroll
    for (int nj = 0; nj < 4; nj++) acc[mi][nj] = (f32x4)(0.f);

  // prologue: stage K-tile 0 in slot order (A-lo, B-lo, B-hi, A-hi)
  stage_Ahalf(Agb, 0, sA, 0, wave, lrow, lcol);
  stage_Bhalf(Bgb, 0, sB, 0, wave, lrow, lcol);
  stage_Bhalf(Bgb, 0, sB, 1, wave, lrow, lcol);
  stage_Ahalf(Agb, 0, sA, 1, wave, lrow, lcol);

  for (int kt = 0; kt < 15; kt++) {
    const unsigned short* Ar = sA + (kt & 1) * 16384;
    const unsigned short* Br = sB + (kt & 1) * 16384;
    unsigned short* Aw = sA + ((kt + 1) & 1) * 16384;
    unsigned short* Bw = sB + ((kt + 1) & 1) * 16384;
    qkv_tile<true, 6, 6, 6>(Agb, Bgb, (kt + 1) * 64, Ar, Br, Aw, Bw,
                            wave, lane, wm, wn, acc);
  }
  // drain tile 15 (parity 1): vmcnt 4 -> 2 -> 0, no staging
  qkv_tile<false, 4, 2, 0>(Agb, Bgb, 0, sA + 16384, sB + 16384, sA, sB,
                           wave, lane, wm, wn, acc);

  const int l16 = lane & 15, rq = lane >> 4;
  int m0 = tM0 + wm * 128;
  asm volatile("" : "+v"(m0));  // block LICM of epilogue addresses into loop
  if (tN0 < 2048) {
#pragma unroll
    for (int mi = 0; mi < 8; mi++) {
      const int m = m0 + mi * 16 + l16;
#pragma unroll
      for (int nj = 0; nj < 4; nj++) {
        const int n = tN0 + wn * 64 + nj * 16 + rq * 4;
        const float4 bv = *(const float4*)&bias[n];
        ushort4 o;
        o.x = f2bf(acc[mi][nj][0] + bv.x);
        o.y = f2bf(acc[mi][nj][1] + bv.y);
        o.z = f2bf(acc[mi][nj][2] + bv.z);
        o.w = f2bf(acc[mi][nj][3] + bv.w);
        *(ushort4*)&qk[(size_t)m * 2048 + n] = o;
      }
    }
  } else {
    const int d0b = tN0 - 2048 + wn * 64;
#pragma unroll
    for (int mi = 0; mi < 8; mi++) {
      const int m = m0 + mi * 16 + l16;
      const int b = m >> 11, ns = m & 2047;
#pragma unroll
      for (int nj = 0; nj < 4; nj++) {
        const int d0 = d0b + nj * 16 + rq * 4;
        const float4 bv = *(const float4*)&bias[2048 + d0];
#pragma unroll
        for (int r = 0; r < 4; r++)
          vT[((size_t)(b * 1024 + d0 + r)) * 2048 + ns] =
              f2bf(acc[mi][nj][r] + ((const float*)&bv)[r]);
      }
    }
  }
}

// --------------------- 128x64 tile machinery (scores/pv) -------------------
__device__ inline void compute_tiles64(const unsigned short* As, const unsigned short* Bs,
                                       int lane, int ry, int rx, f32x4 acc[4][2]) {
#pragma unroll
  for (int kk = 0; kk < 64; kk += 32) {
    const int cbase = (kk >> 3) + (lane >> 4);
    const int csw = ((cbase ^ (lane & 7)) << 3);
    bf16x8 a[4], b[2];
#pragma unroll
    for (int mi = 0; mi < 4; mi++)
      a[mi] = *(const bf16x8*)&As[(ry + mi * 16 + (lane & 15)) * 64 + csw];
#pragma unroll
    for (int nj = 0; nj < 2; nj++)
      b[nj] = *(const bf16x8*)&Bs[(rx + nj * 16 + (lane & 15)) * 64 + csw];
#pragma unroll
    for (int mi = 0; mi < 4; mi++)
#pragma unroll
      for (int nj = 0; nj < 2; nj++)
        acc[mi][nj] = __builtin_amdgcn_mfma_f32_16x16x32_bf16(b[nj], a[mi], acc[mi][nj], 0, 0, 0);
  }
}

__device__ inline void mma_mainloop64(unsigned short* As, unsigned short* Bs,
                                      const unsigned short* Abase, long strideA,
                                      const unsigned short* Bbase, long strideB,
                                      int kIters, f32x4 acc[4][2]) {
  const int lane = threadIdx.x & 63, wave = threadIdx.x >> 6;
  const int ry = (wave >> 1) * 64, rx = (wave & 1) * 32;
  const int lrow = lane >> 3;
  const int lcol = ((lane & 7) ^ lrow) * 8;
#pragma unroll
  for (int mi = 0; mi < 4; mi++)
#pragma unroll
    for (int nj = 0; nj < 2; nj++) acc[mi][nj] = (f32x4)(0.f);
  for (int kt = 0; kt < kIters; kt++) {
    const int k0 = kt * 64;
    __syncthreads();
#pragma unroll
    for (int c = 0; c < 4; c++) {  // A: 16 chunks of 8 rows -> 4 per wave
      const int q = wave * 4 + c;
      const int row = q * 8 + lrow;
      gld16(Abase + (size_t)row * strideA + k0 + lcol, &As[q * 512]);
    }
#pragma unroll
    for (int c = 0; c < 2; c++) {  // B: 8 chunks -> 2 per wave
      const int q = wave * 2 + c;
      const int row = q * 8 + lrow;
      gld16(Bbase + (size_t)row * strideB + k0 + lcol, &Bs[q * 512]);
    }
    __syncthreads();
    compute_tiles64(As, Bs, lane, ry, rx, acc);
  }
}

// --------------------------- prep kernels ----------------------------------

__global__ void k_convert(const float* __restrict__ x, unsigned short* __restrict__ y, int n4) {
  int i = blockIdx.x * blockDim.x + threadIdx.x;
  if (i >= n4) return;
  float4 v = ((const float4*)x)[i];
  ushort4 o;
  o.x = f2bf(v.x); o.y = f2bf(v.y); o.z = f2bf(v.z); o.w = f2bf(v.w);
  ((ushort4*)y)[i] = o;
}

// W [1024][3072] fp32 -> Wt [3072][1024] bf16
__global__ void k_transpose_w(const float* __restrict__ W, unsigned short* __restrict__ Wt) {
  __shared__ unsigned short sm[64 * 65];
  const int n0 = blockIdx.x * 64;
  const int k0 = blockIdx.y * 64;
  for (int i = threadIdx.x; i < 4096; i += 256) {
    int r = i >> 6, c = i & 63;
    sm[c * 65 + r] = f2bf(W[(size_t)(k0 + r) * 3072 + n0 + c]);
  }
  __syncthreads();
  for (int i = threadIdx.x; i < 4096; i += 256) {
    int r = i >> 6, c = i & 63;
    Wt[(size_t)(n0 + r) * 1024 + k0 + c] = sm[r * 65 + c];
  }
}

// ------------------------- scores / pv kernels -----------------------------

// P_unnorm 128x64 tile + row-sum atomics. Triangular 1-D grid over
// (qb in 16, kb2 in 2qb+2), z = batch. 272 tiles/batch.
__global__ __launch_bounds__(256) void k_scores(const unsigned short* __restrict__ qk,
                                                unsigned short* __restrict__ P,
                                                float* __restrict__ l, float scale) {
  __shared__ unsigned short As[128 * 64];
  __shared__ unsigned short Bs[64 * 64];
  const int t = blockIdx.x, b = blockIdx.z;
  int qb = (int)((sqrtf(4.0f * (float)t + 1.0f) - 1.0f) * 0.5f);  // qb^2+qb <= t
  while (qb * (qb + 1) > t) qb--;
  while ((qb + 1) * (qb + 2) <= t) qb++;
  const int kb2 = t - qb * (qb + 1);  // 64-wide k tile, 0..2qb+1
  f32x4 acc[4][2];
  const unsigned short* Aq = qk + ((size_t)(b * 2048 + qb * 128)) * 2048;
  const unsigned short* Bk = qk + ((size_t)(b * 2048 + kb2 * 64)) * 2048 + 1024;
  mma_mainloop64(As, Bs, Aq, 2048, Bk, 2048, 16, acc);
  const int lane = threadIdx.x & 63, wave = threadIdx.x >> 6;
  const int ry = (wave >> 1) * 64, rx = (wave & 1) * 32;
  const int l16 = lane & 15, rq = lane >> 4;
  unsigned short* Pb = P + ((size_t)(b * 2048 + qb * 128)) * 2048 + (size_t)kb2 * 64;
  float* lb = l + b * 2048 + qb * 128;
#pragma unroll
  for (int mi = 0; mi < 4; mi++) {
    const int m_local = ry + mi * 16 + l16;
    const int qi = qb * 128 + m_local;
    float rowpart = 0.f;
#pragma unroll
    for (int nj = 0; nj < 2; nj++) {
      const int n_base = rx + nj * 16 + rq * 4;
      ushort4 o;
      float p;
#pragma unroll
      for (int r = 0; r < 4; r++) {
        const int kj = kb2 * 64 + n_base + r;
        p = (kj <= qi) ? __expf(acc[mi][nj][r] * scale) : 0.f;
        rowpart += p;
        ((unsigned short*)&o)[r] = f2bf(p);
      }
      *(ushort4*)&Pb[(size_t)m_local * 2048 + n_base] = o;
    }
    rowpart += __shfl_xor(rowpart, 16, 64);
    rowpart += __shfl_xor(rowpart, 32, 64);
    if (rq == 0) atomicAdd(&lb[m_local], rowpart);
  }
}

// out[m][d] = (P[m][:] @ vT[d][:]) / l[m].  128x64 tiles: grid (db2 16, qb 16,
// b 4); causal k-range (qb+1)*2 chunks; qb flipped on half the batches.
__global__ __launch_bounds__(256) void k_pv(const unsigned short* __restrict__ P,
                                            const unsigned short* __restrict__ vT,
                                            const float* __restrict__ l,
                                            float* __restrict__ out) {
  __shared__ unsigned short As[128 * 64];
  __shared__ unsigned short Bs[64 * 64];
  const int db2 = blockIdx.x, b = blockIdx.z;
  int qb = blockIdx.y;
  if (b & 2) qb = 15 - qb;  // balance causal depth across CUs
  f32x4 acc[4][2];
  const unsigned short* Ap = P + ((size_t)(b * 2048 + qb * 128)) * 2048;
  const unsigned short* Bv = vT + ((size_t)(b * 1024 + db2 * 64)) * 2048;
  mma_mainloop64(As, Bs, Ap, 2048, Bv, 2048, (qb + 1) * 2, acc);
  const int lane = threadIdx.x & 63, wave = threadIdx.x >> 6;
  const int ry = (wave >> 1) * 64, rx = (wave & 1) * 32;
  const int l16 = lane & 15, rq = lane >> 4;
  const float* lb = l + b * 2048 + qb * 128;
  float* ob = out + ((size_t)(b * 2048 + qb * 128)) * 1024 + db2 * 64;
#pragma unroll
  for (int mi = 0; mi < 4; mi++) {
    const int m_local = ry + mi * 16 + l16;
    const float inv = 1.0f / lb[m_local];
#pragma unroll
    for (int nj = 0; nj < 2; nj++) {
      const int n_base = rx + nj * 16 + rq * 4;
      float4 o;
      o.x = acc[mi][nj][0] * inv;
      o.y = acc[mi][nj][1] * inv;
      o.z = acc[mi][nj][2] * inv;
      o.w = acc[mi][nj][3] * inv;
      *(float4*)&ob[(size_t)m_local * 1024 + n_base] = o;
    }
  }
}

// ---------------------------------------------------------------------------

extern "C" void kernel_launch(void* const* d_in, const int* in_sizes, int n_in,
                              void* d_out, int out_size, void* d_ws, size_t ws_size,
                              hipStream_t stream) {
  const float* ctx  = (const float*)d_in[0];  // [4,2048,1024]
  const float* W    = (const float*)d_in[1];  // [1024,3072]
  const float* bias = (const float*)d_in[2];  // [3072]
  float* out = (float*)d_out;

  char* ws = (char*)d_ws;
  unsigned short* Actx = (unsigned short*)(ws + 0);          // 16,777,216
  unsigned short* Wt   = (unsigned short*)(ws + 16777216);   //  6,291,456
  unsigned short* qk   = (unsigned short*)(ws + 23068672);   // 33,554,432
  unsigned short* vT   = (unsigned short*)(ws + 56623104);   // 16,777,216
  unsigned short* P    = (unsigned short*)(ws + 73400320);   // 33,554,432
  float*          lsum = (float*)(ws + 106954752);           //     32,768

  hipMemsetAsync(lsum, 0, 4 * 2048 * sizeof(float), stream);
  k_convert<<<8192, 256, 0, stream>>>(ctx, Actx, (8192 * 1024) / 4);
  k_transpose_w<<<dim3(48, 16), 256, 0, stream>>>(W, Wt);
  k_gemm_qkv<<<dim3(12, 32), 512, 0, stream>>>(Actx, Wt, bias, qk, vT);
  k_scores<<<dim3(272, 1, 4), 256, 0, stream>>>(qk, P, lsum, 0.022097086912079608f);
  k_pv<<<dim3(16, 16, 4), 256, 0, stream>>>(P, vT, lsum, out);
}